// Round 2
// baseline (6250.268 us; speedup 1.0000x reference)
//
#include <hip/hip_runtime.h>
#include <math.h>

#define BB 8
#define NN 1024
#define CC 16
#define SS 32
#define LLAYERS 8
#define HH 8

// Blade metadata (reference blade ordering):
// 0:() 1:(0) 2:(1) 3:(2) 4:(3) 5:(01) 6:(02) 7:(03) 8:(12) 9:(13) 10:(23)
// 11:(012) 12:(013) 13:(023) 14:(123) 15:(0123)
__constant__ int d_GRADE[16] = {0,1,1,1,1,2,2,2,2,2,2,3,3,3,3,4};
__constant__ int d_PAIR[16]  = {-1,0,-1,-1,-1,2,3,4,-1,-1,-1,8,9,10,-1,14};
__constant__ int d_INNER[16] = {1,0,1,1,1,0,0,0,1,1,1,0,0,0,1,0};
// position of blade within the 8 INNER (e0-free) blades, -1 otherwise
__constant__ int d_IPOS[16]  = {0,-1,1,2,3,-1,-1,-1,4,5,6,-1,-1,-1,7,-1};
// blade index -> bitmask over {e0,e1,e2,e3}
__constant__ int d_I2M[16] = {0,1,2,4,8,3,5,9,6,10,12,7,11,13,14,15};
// bitmask -> blade index
__constant__ int d_M2I[16] = {0,1,2,5,3,6,8,11,4,7,9,12,10,13,14,15};

#define ATTN_SCALE 0.22360679774997896f  // 1/sqrt(8*2 + 4)

__device__ __forceinline__ float gelu_tanh(float x) {
  // jax.nn.gelu approximate=True
  float x3 = x * x * x;
  float inner = 0.7978845608028654f * (x + 0.044715f * x3);
  return 0.5f * x * (1.0f + tanhf(inner));
}

// ---------------- embed ----------------
__global__ void __launch_bounds__(256) k_embed(
    const float* __restrict__ inp, const float* __restrict__ win_mv,
    const float* __restrict__ win_ms, const float* __restrict__ win_bs,
    float* __restrict__ mv, float* __restrict__ s)
{
  int tok = blockIdx.x, t = threadIdx.x;
  float x = inp[tok * 3 + 0];
  float y = inp[tok * 3 + 1];
  float z = inp[tok * 3 + 2];
  int o = t >> 4, aa = t & 15;
  float ma = (aa == 14) ? 1.f : (aa == 13) ? -x : (aa == 12) ? y : (aa == 11) ? -z : 0.f;
  int g = d_GRADE[aa];
  float val = win_mv[o * 9 + g] * ma;
  int pr = d_PAIR[aa];
  if (pr >= 0) {
    float mp = (pr == 14) ? 1.f : 0.f;  // other pair blades are zero in mv0
    val += win_mv[o * 9 + 4 + g] * mp;
  }
  mv[(size_t)tok * 256 + t] = val;
  if (t < 32) s[(size_t)tok * 32 + t] = win_bs[t];
  (void)win_ms;
}

// ---------------- LN + QKV projection (writes attention-packed buffers) ----------------
// q_pack[(b*8+h)*1024+n][20] : 16 INNER mv dims (2ch x 8) * scale, then 4 s dims * scale
// k_pack[(b*8+h)*1024+n][20] : same layout, unscaled
// v_pack[(b*8+h)*1024+n][36] : full 32 mv dims (2ch x 16), then 4 s dims
__global__ void __launch_bounds__(256) k_ln_qkv(
    const float* __restrict__ mv, const float* __restrict__ s,
    const float* __restrict__ wmv, const float* __restrict__ wsm,
    const float* __restrict__ wms, const float* __restrict__ wss,
    float* __restrict__ q_pack, float* __restrict__ k_pack, float* __restrict__ v_pack)
{
  __shared__ float nmv[256];
  __shared__ float ns[32];
  __shared__ float red[256];
  int tok = blockIdx.x, t = threadIdx.x;
  int b = tok >> 10, n = tok & 1023;
  int aa = t & 15;
  float v = mv[(size_t)tok * 256 + t];
  float sv = (t < 32) ? s[(size_t)tok * 32 + t] : 0.f;
  red[t] = d_INNER[aa] ? v * v : 0.f;
  __syncthreads();
  for (int w = 128; w > 0; w >>= 1) { if (t < w) red[t] += red[t + w]; __syncthreads(); }
  float inv = rsqrtf(red[0] / 16.f + 1e-6f);
  __syncthreads();
  red[t] = (t < 32) ? sv * sv : 0.f;
  __syncthreads();
  for (int w = 128; w > 0; w >>= 1) { if (t < w) red[t] += red[t + w]; __syncthreads(); }
  float sinv = rsqrtf(red[0] / 32.f + 1e-6f);
  nmv[t] = v * inv;
  if (t < 32) ns[t] = sv * sinv;
  __syncthreads();

  for (int r = 0; r < 3; ++r) {
    int u = r * 256 + t;
    int o = u >> 4, a2 = u & 15;
    int sec = o >> 4;          // 0=q, 1=k, 2=v
    int c2 = o & 15;           // channel within section
    int h = c2 >> 1, c = c2 & 1;
    int g = d_GRADE[a2];
    const float* w = wmv + (size_t)o * 16 * 9;
    float yy = 0.f;
    #pragma unroll
    for (int i = 0; i < 16; ++i) yy += w[i * 9 + g] * nmv[i * 16 + a2];
    int pr = d_PAIR[a2];
    if (pr >= 0) {
      int k2 = 4 + g;
      #pragma unroll
      for (int i = 0; i < 16; ++i) yy += w[i * 9 + k2] * nmv[i * 16 + pr];
    }
    if (a2 == 0) {
      const float* wr = wsm + (size_t)o * 32;
      #pragma unroll
      for (int j = 0; j < 32; ++j) yy += wr[j] * ns[j];
    }
    size_t kvb = ((size_t)(b * 8 + h)) * 1024 + n;
    if (sec == 0) {
      int ip = d_IPOS[a2];
      if (ip >= 0) q_pack[kvb * 20 + c * 8 + ip] = yy * ATTN_SCALE;
    } else if (sec == 1) {
      int ip = d_IPOS[a2];
      if (ip >= 0) k_pack[kvb * 20 + c * 8 + ip] = yy;
    } else {
      v_pack[kvb * 36 + c * 16 + a2] = yy;
    }
  }
  if (t < 96) {
    float yy = 0.f;
    const float* w1 = wss + (size_t)t * 32;
    #pragma unroll
    for (int j = 0; j < 32; ++j) yy += w1[j] * ns[j];
    const float* w2 = wms + (size_t)t * 16;
    #pragma unroll
    for (int i = 0; i < 16; ++i) yy += w2[i] * nmv[i * 16];
    int sec = t >> 5, o2 = t & 31;
    int h = o2 >> 2, d = o2 & 3;
    size_t kvb = ((size_t)(b * 8 + h)) * 1024 + n;
    if (sec == 0)      q_pack[kvb * 20 + 16 + d] = yy * ATTN_SCALE;
    else if (sec == 1) k_pack[kvb * 20 + 16 + d] = yy;
    else               v_pack[kvb * 36 + 32 + d] = yy;
  }
}

// ---------------- attention ----------------
// block = 1024 threads: 4 key-groups x 256 queries; flash-decoding merge in LDS.
// K/V read directly from global with wave-uniform (broadcast) float4 loads.
__global__ void __launch_bounds__(1024) k_attn(
    const float* __restrict__ q_pack, const float* __restrict__ k_pack,
    const float* __restrict__ v_pack, float* __restrict__ o_mv, float* __restrict__ o_s)
{
  __shared__ float mrg[256 * 41];
  int bx = blockIdx.x;
  int qt = bx & 3, h = (bx >> 2) & 7, b = bx >> 5;
  int t = threadIdx.x;
  int ql = t & 255, g = t >> 8;
  int n = qt * 256 + ql;
  size_t hb = ((size_t)(b * 8 + h)) * 1024;

  float4 qv[5];
  {
    const float4* qp = (const float4*)(q_pack + (hb + n) * 20);
    #pragma unroll
    for (int u = 0; u < 5; ++u) qv[u] = qp[u];
  }

  float4 acc[9];
  #pragma unroll
  for (int u = 0; u < 9; ++u) acc[u] = make_float4(0.f, 0.f, 0.f, 0.f);
  float m = -1e30f, l = 0.f;

  const float4* kbase = (const float4*)(k_pack + (hb + (size_t)g * 256) * 20);
  const float4* vbase = (const float4*)(v_pack + (hb + (size_t)g * 256) * 36);

  #pragma unroll 2
  for (int kk = 0; kk < 256; ++kk) {
    const float4* kp = kbase + kk * 5;
    float sc = 0.f;
    #pragma unroll
    for (int u = 0; u < 5; ++u) {
      float4 kv = kp[u];
      sc += qv[u].x * kv.x + qv[u].y * kv.y + qv[u].z * kv.z + qv[u].w * kv.w;
    }
    float nm = fmaxf(m, sc);
    float corr = __expf(m - nm);
    float p = __expf(sc - nm);
    m = nm;
    l = l * corr + p;
    const float4* vp = vbase + kk * 9;
    #pragma unroll
    for (int u = 0; u < 9; ++u) {
      float4 vv = vp[u];
      acc[u].x = acc[u].x * corr + p * vv.x;
      acc[u].y = acc[u].y * corr + p * vv.y;
      acc[u].z = acc[u].z * corr + p * vv.z;
      acc[u].w = acc[u].w * corr + p * vv.w;
    }
  }

  // merge the 4 partials per query (serial rounds; group 0 accumulates)
  for (int r = 1; r < 4; ++r) {
    __syncthreads();
    if (g == r) {
      float* mp = &mrg[ql * 41];
      #pragma unroll
      for (int u = 0; u < 9; ++u) {
        mp[u * 4 + 0] = acc[u].x; mp[u * 4 + 1] = acc[u].y;
        mp[u * 4 + 2] = acc[u].z; mp[u * 4 + 3] = acc[u].w;
      }
      mp[36] = m; mp[37] = l;
    }
    __syncthreads();
    if (g == 0) {
      float* mp = &mrg[ql * 41];
      float m2 = mp[36], l2 = mp[37];
      float nm = fmaxf(m, m2);
      float c1 = __expf(m - nm), c2 = __expf(m2 - nm);
      m = nm;
      l = l * c1 + l2 * c2;
      #pragma unroll
      for (int u = 0; u < 9; ++u) {
        acc[u].x = acc[u].x * c1 + mp[u * 4 + 0] * c2;
        acc[u].y = acc[u].y * c1 + mp[u * 4 + 1] * c2;
        acc[u].z = acc[u].z * c1 + mp[u * 4 + 2] * c2;
        acc[u].w = acc[u].w * c1 + mp[u * 4 + 3] * c2;
      }
    }
  }

  if (g == 0) {
    float invl = 1.f / l;
    float* op = o_mv + ((size_t)(b * NN + n) * 16 + 2 * h) * 16;
    #pragma unroll
    for (int u = 0; u < 8; ++u) {
      float4 av = acc[u];
      av.x *= invl; av.y *= invl; av.z *= invl; av.w *= invl;
      *(float4*)(op + u * 4) = av;
    }
    float* osp = o_s + (size_t)(b * NN + n) * 32 + 4 * h;
    osp[0] = acc[8].x * invl;
    osp[1] = acc[8].y * invl;
    osp[2] = acc[8].z * invl;
    osp[3] = acc[8].w * invl;
  }
}

// ---------------- attention out-proj + residual ----------------
__global__ void __launch_bounds__(256) k_out_res(
    const float* __restrict__ o_mv, const float* __restrict__ o_s,
    const float* __restrict__ wmv, const float* __restrict__ wsm,
    const float* __restrict__ wms, const float* __restrict__ wss,
    float* __restrict__ mv, float* __restrict__ s)
{
  __shared__ float x[256];
  __shared__ float xs[32];
  int tok = blockIdx.x, t = threadIdx.x;
  x[t] = o_mv[(size_t)tok * 256 + t];
  if (t < 32) xs[t] = o_s[(size_t)tok * 32 + t];
  __syncthreads();
  int o = t >> 4, aa = t & 15;
  int g = d_GRADE[aa];
  const float* w = wmv + (size_t)o * 16 * 9;
  float yy = 0.f;
  #pragma unroll
  for (int i = 0; i < 16; ++i) yy += w[i * 9 + g] * x[i * 16 + aa];
  int pr = d_PAIR[aa];
  if (pr >= 0) {
    int k2 = 4 + g;
    #pragma unroll
    for (int i = 0; i < 16; ++i) yy += w[i * 9 + k2] * x[i * 16 + pr];
  }
  if (aa == 0) {
    const float* wr = wsm + (size_t)o * 32;
    #pragma unroll
    for (int j = 0; j < 32; ++j) yy += wr[j] * xs[j];
  }
  mv[(size_t)tok * 256 + t] += yy;
  if (t < 32) {
    float ys = 0.f;
    const float* w1 = wss + (size_t)t * 32;
    #pragma unroll
    for (int j = 0; j < 32; ++j) ys += w1[j] * xs[j];
    const float* w2 = wms + (size_t)t * 16;
    #pragma unroll
    for (int i = 0; i < 16; ++i) ys += w2[i] * x[i * 16];
    s[(size_t)tok * 32 + t] += ys;
  }
}

// ---------------- LN + geometric MLP + residual ----------------
__global__ void __launch_bounds__(256) k_mlp_res(
    float* __restrict__ mv, float* __restrict__ s,
    const float* __restrict__ w1mv, const float* __restrict__ w1sm,
    const float* __restrict__ w1ms, const float* __restrict__ w1ss,
    const float* __restrict__ w2mv, const float* __restrict__ w2sm,
    const float* __restrict__ w2ms, const float* __restrict__ w2ss)
{
  __shared__ float nmv[256];
  __shared__ float ns[32];
  __shared__ float red[256];
  __shared__ float hmv[512];
  __shared__ float hs[64];
  __shared__ float gpl[256];
  __shared__ float shl[32];
  int tok = blockIdx.x, t = threadIdx.x;
  int aa = t & 15;
  float v = mv[(size_t)tok * 256 + t];
  float sv = (t < 32) ? s[(size_t)tok * 32 + t] : 0.f;
  red[t] = d_INNER[aa] ? v * v : 0.f;
  __syncthreads();
  for (int w = 128; w > 0; w >>= 1) { if (t < w) red[t] += red[t + w]; __syncthreads(); }
  float inv = rsqrtf(red[0] / 16.f + 1e-6f);
  __syncthreads();
  red[t] = (t < 32) ? sv * sv : 0.f;
  __syncthreads();
  for (int w = 128; w > 0; w >>= 1) { if (t < w) red[t] += red[t + w]; __syncthreads(); }
  float sinv = rsqrtf(red[0] / 32.f + 1e-6f);
  nmv[t] = v * inv;
  if (t < 32) ns[t] = sv * sinv;
  __syncthreads();

  for (int r = 0; r < 2; ++r) {
    int u = r * 256 + t;
    int o = u >> 4, a2 = u & 15;
    int g = d_GRADE[a2];
    const float* w = w1mv + (size_t)o * 16 * 9;
    float yy = 0.f;
    #pragma unroll
    for (int i = 0; i < 16; ++i) yy += w[i * 9 + g] * nmv[i * 16 + a2];
    int pr = d_PAIR[a2];
    if (pr >= 0) {
      int k2 = 4 + g;
      #pragma unroll
      for (int i = 0; i < 16; ++i) yy += w[i * 9 + k2] * nmv[i * 16 + pr];
    }
    if (a2 == 0) {
      const float* wr = w1sm + (size_t)o * 32;
      #pragma unroll
      for (int j = 0; j < 32; ++j) yy += wr[j] * ns[j];
    }
    hmv[u] = yy;
  }
  if (t < 64) {
    float yy = 0.f;
    const float* w1 = w1ss + (size_t)t * 32;
    #pragma unroll
    for (int j = 0; j < 32; ++j) yy += w1[j] * ns[j];
    const float* w2 = w1ms + (size_t)t * 16;
    #pragma unroll
    for (int i = 0; i < 16; ++i) yy += w2[i] * nmv[i * 16];
    hs[t] = yy;
  }
  __syncthreads();

  int c = t >> 4, k = t & 15;
  int mk = d_I2M[k];
  float gacc = 0.f;
  #pragma unroll
  for (int i = 0; i < 16; ++i) {
    int mi = d_I2M[i];
    int mj = mi ^ mk;
    if (mi & mj & 1) continue;  // e0 * e0 = 0
    int j = d_M2I[mj];
    int sw = 0;
    #pragma unroll
    for (int bb = 0; bb < 4; ++bb)
      if (mj & (1 << bb)) sw += __popc(((unsigned)mi) >> (bb + 1));
    float val = hmv[c * 16 + i] * hmv[256 + c * 16 + j];
    gacc += (sw & 1) ? -val : val;
  }
  gpl[t] = gacc;
  __syncthreads();
  float g0 = gpl[c * 16];
  __syncthreads();
  gpl[t] = gacc * gelu_tanh(g0);
  if (t < 32) shl[t] = hs[t] * gelu_tanh(hs[32 + t]);
  __syncthreads();

  {
    int o = t >> 4;
    int g = d_GRADE[aa];
    const float* w = w2mv + (size_t)o * 16 * 9;
    float yy = 0.f;
    #pragma unroll
    for (int i = 0; i < 16; ++i) yy += w[i * 9 + g] * gpl[i * 16 + aa];
    int pr = d_PAIR[aa];
    if (pr >= 0) {
      int k2 = 4 + g;
      #pragma unroll
      for (int i = 0; i < 16; ++i) yy += w[i * 9 + k2] * gpl[i * 16 + pr];
    }
    if (aa == 0) {
      const float* wr = w2sm + (size_t)o * 32;
      #pragma unroll
      for (int j = 0; j < 32; ++j) yy += wr[j] * shl[j];
    }
    mv[(size_t)tok * 256 + t] = v + yy;
  }
  if (t < 32) {
    float ys = 0.f;
    const float* w1 = w2ss + (size_t)t * 32;
    #pragma unroll
    for (int j = 0; j < 32; ++j) ys += w1[j] * shl[j];
    const float* w2 = w2ms + (size_t)t * 16;
    #pragma unroll
    for (int i = 0; i < 16; ++i) ys += w2[i] * gpl[i * 16];
    s[(size_t)tok * 32 + t] = sv + ys;
  }
}

// ---------------- final projection + mean ----------------
__global__ void __launch_bounds__(256) k_final(
    const float* __restrict__ mv, const float* __restrict__ s,
    const float* __restrict__ wout_mv, const float* __restrict__ wout_sm,
    float* __restrict__ out)
{
  __shared__ float red[256];
  int b = blockIdx.x, t = threadIdx.x;
  float part = 0.f;
  for (int n = t; n < NN; n += 256) {
    const float* mvp = mv + ((size_t)(b * NN + n) * 16) * 16;
    const float* sp = s + (size_t)(b * NN + n) * 32;
    float acc = 0.f;
    #pragma unroll
    for (int i = 0; i < 16; ++i) acc += wout_mv[i * 9] * mvp[i * 16];
    #pragma unroll
    for (int j = 0; j < 32; ++j) acc += wout_sm[j] * sp[j];
    part += acc;
  }
  red[t] = part;
  __syncthreads();
  for (int w = 128; w > 0; w >>= 1) { if (t < w) red[t] += red[t + w]; __syncthreads(); }
  if (t == 0) out[b] = red[0] / (float)NN;
}

extern "C" void kernel_launch(void* const* d_in, const int* in_sizes, int n_in,
                              void* d_out, int out_size, void* d_ws, size_t ws_size,
                              hipStream_t stream) {
  const float* inputs    = (const float*)d_in[0];
  const float* win_mv    = (const float*)d_in[1];
  const float* win_ms    = (const float*)d_in[2];
  const float* win_bs    = (const float*)d_in[3];
  const float* a_qkv_wmv = (const float*)d_in[4];
  const float* a_qkv_wsm = (const float*)d_in[5];
  const float* a_qkv_wms = (const float*)d_in[6];
  const float* a_qkv_wss = (const float*)d_in[7];
  const float* a_out_wmv = (const float*)d_in[8];
  const float* a_out_wsm = (const float*)d_in[9];
  const float* a_out_wms = (const float*)d_in[10];
  const float* a_out_wss = (const float*)d_in[11];
  const float* m1_wmv    = (const float*)d_in[12];
  const float* m1_wsm    = (const float*)d_in[13];
  const float* m1_wms    = (const float*)d_in[14];
  const float* m1_wss    = (const float*)d_in[15];
  const float* m2_wmv    = (const float*)d_in[16];
  const float* m2_wsm    = (const float*)d_in[17];
  const float* m2_wms    = (const float*)d_in[18];
  const float* m2_wss    = (const float*)d_in[19];
  const float* wout_mv   = (const float*)d_in[20];
  const float* wout_sm   = (const float*)d_in[21];
  float* out = (float*)d_out;

  float* ws = (float*)d_ws;
  float* mv     = ws;                    // 8*1024*16*16 = 2097152
  float* s      = mv + 2097152;          // 8*1024*32    = 262144
  float* q_pack = s + 262144;            // 8*8*1024*20  = 1310720
  float* k_pack = q_pack + 1310720;      // 1310720
  float* v_pack = k_pack + 1310720;      // 8*8*1024*36  = 2359296
  float* o_mv   = v_pack + 2359296;      // 2097152
  float* o_s    = o_mv + 2097152;        // 262144  -> total 9699328 floats = 38.8 MB

  int ntok = BB * NN;
  k_embed<<<ntok, 256, 0, stream>>>(inputs, win_mv, win_ms, win_bs, mv, s);

  for (int l = 0; l < LLAYERS; ++l) {
    k_ln_qkv<<<ntok, 256, 0, stream>>>(mv, s,
        a_qkv_wmv + (size_t)l * 48 * 16 * 9, a_qkv_wsm + (size_t)l * 48 * 32,
        a_qkv_wms + (size_t)l * 96 * 16,     a_qkv_wss + (size_t)l * 96 * 32,
        q_pack, k_pack, v_pack);
    k_attn<<<BB * HH * 4, 1024, 0, stream>>>(q_pack, k_pack, v_pack, o_mv, o_s);
    k_out_res<<<ntok, 256, 0, stream>>>(o_mv, o_s,
        a_out_wmv + (size_t)l * 16 * 16 * 9, a_out_wsm + (size_t)l * 16 * 32,
        a_out_wms + (size_t)l * 32 * 16,     a_out_wss + (size_t)l * 32 * 32,
        mv, s);
    k_mlp_res<<<ntok, 256, 0, stream>>>(mv, s,
        m1_wmv + (size_t)l * 32 * 16 * 9, m1_wsm + (size_t)l * 32 * 32,
        m1_wms + (size_t)l * 64 * 16,     m1_wss + (size_t)l * 64 * 32,
        m2_wmv + (size_t)l * 16 * 16 * 9, m2_wsm + (size_t)l * 16 * 32,
        m2_wms + (size_t)l * 32 * 16,     m2_wss + (size_t)l * 32 * 32);
  }

  k_final<<<BB, 256, 0, stream>>>(mv, s, wout_mv, wout_sm, out);

  (void)in_sizes; (void)n_in; (void)out_size; (void)ws_size;
}

// Round 3
// 2292.787 us; speedup vs baseline: 2.7261x; 2.7261x over previous
//
#include <hip/hip_runtime.h>
#include <math.h>

#define BB 8
#define NN 1024
#define CC 16
#define SS 32
#define LLAYERS 8
#define HH 8

typedef unsigned short ushort_t;
using bf16x8 = __attribute__((ext_vector_type(8))) short;
using f32x4  = __attribute__((ext_vector_type(4))) float;

// Blade metadata (reference blade ordering):
// 0:() 1:(0) 2:(1) 3:(2) 4:(3) 5:(01) 6:(02) 7:(03) 8:(12) 9:(13) 10:(23)
// 11:(012) 12:(013) 13:(023) 14:(123) 15:(0123)
__constant__ int d_GRADE[16] = {0,1,1,1,1,2,2,2,2,2,2,3,3,3,3,4};
__constant__ int d_PAIR[16]  = {-1,0,-1,-1,-1,2,3,4,-1,-1,-1,8,9,10,-1,14};
__constant__ int d_INNER[16] = {1,0,1,1,1,0,0,0,1,1,1,0,0,0,1,0};
// position of blade within the 8 INNER (e0-free) blades, -1 otherwise
__constant__ int d_IPOS[16]  = {0,-1,1,2,3,-1,-1,-1,4,5,6,-1,-1,-1,7,-1};
// position within the 8 non-INNER blades, -1 otherwise (for zero-pad slot mapping)
__constant__ int d_JPOS[16]  = {-1,0,-1,-1,-1,1,2,3,-1,-1,-1,4,5,6,-1,7};
// blade index -> bitmask over {e0,e1,e2,e3}
__constant__ int d_I2M[16] = {0,1,2,4,8,3,5,9,6,10,12,7,11,13,14,15};
// bitmask -> blade index
__constant__ int d_M2I[16] = {0,1,2,5,3,6,8,11,4,7,9,12,10,13,14,15};

// softmax in log2 domain: fold 1/sqrt(20) * log2(e) into Q at pack time
#define QSCALE (0.22360679774997896f * 1.4426950408889634f)

__device__ __forceinline__ float gelu_tanh(float x) {
  float x3 = x * x * x;
  float inner = 0.7978845608028654f * (x + 0.044715f * x3);
  return 0.5f * x * (1.0f + tanhf(inner));
}

__device__ __forceinline__ ushort_t f2b(float f) {
  union { float f; unsigned int u; } x;
  x.f = f;
  unsigned int r = x.u + 0x7fffu + ((x.u >> 16) & 1u);  // RNE
  return (ushort_t)(r >> 16);
}

// ---------------- embed ----------------
__global__ void __launch_bounds__(256) k_embed(
    const float* __restrict__ inp, const float* __restrict__ win_mv,
    const float* __restrict__ win_ms, const float* __restrict__ win_bs,
    float* __restrict__ mv, float* __restrict__ s)
{
  int tok = blockIdx.x, t = threadIdx.x;
  float x = inp[tok * 3 + 0];
  float y = inp[tok * 3 + 1];
  float z = inp[tok * 3 + 2];
  int o = t >> 4, aa = t & 15;
  float ma = (aa == 14) ? 1.f : (aa == 13) ? -x : (aa == 12) ? y : (aa == 11) ? -z : 0.f;
  int g = d_GRADE[aa];
  float val = win_mv[o * 9 + g] * ma;
  int pr = d_PAIR[aa];
  if (pr >= 0) {
    float mp = (pr == 14) ? 1.f : 0.f;
    val += win_mv[o * 9 + 4 + g] * mp;
  }
  mv[(size_t)tok * 256 + t] = val;
  if (t < 32) s[(size_t)tok * 32 + t] = win_bs[t];
  (void)win_ms;
}

// ---------------- LN + QKV projection (writes bf16 MFMA-packed buffers) ----------------
// q_bf[(b*8+h)*1024+n][32] bf16: d0-7 = ch0 INNER blades *QSCALE, d8-15 = ch1 INNER,
//                                d16-19 = s dims *QSCALE, d20-31 = 0
// k_bf: same layout, unscaled
// vT  [(b*8+h)*48 + vdim][1024] bf16: vdim = c*16+blade (0-31), 32-35 = s dims, 36-47 unused
__global__ void __launch_bounds__(256) k_ln_qkv(
    const float* __restrict__ mv, const float* __restrict__ s,
    const float* __restrict__ wmv, const float* __restrict__ wsm,
    const float* __restrict__ wms, const float* __restrict__ wss,
    ushort_t* __restrict__ q_bf, ushort_t* __restrict__ k_bf, ushort_t* __restrict__ vT)
{
  __shared__ float nmv[256];
  __shared__ float ns[32];
  __shared__ float red[256];
  int tok = blockIdx.x, t = threadIdx.x;
  int b = tok >> 10, n = tok & 1023;
  int aa = t & 15;
  float v = mv[(size_t)tok * 256 + t];
  float sv = (t < 32) ? s[(size_t)tok * 32 + t] : 0.f;
  red[t] = d_INNER[aa] ? v * v : 0.f;
  __syncthreads();
  for (int w = 128; w > 0; w >>= 1) { if (t < w) red[t] += red[t + w]; __syncthreads(); }
  float inv = rsqrtf(red[0] / 16.f + 1e-6f);
  __syncthreads();
  red[t] = (t < 32) ? sv * sv : 0.f;
  __syncthreads();
  for (int w = 128; w > 0; w >>= 1) { if (t < w) red[t] += red[t + w]; __syncthreads(); }
  float sinv = rsqrtf(red[0] / 32.f + 1e-6f);
  nmv[t] = v * inv;
  if (t < 32) ns[t] = sv * sinv;
  __syncthreads();

  for (int r = 0; r < 3; ++r) {
    int u = r * 256 + t;
    int o = u >> 4, a2 = u & 15;
    int sec = o >> 4;          // 0=q, 1=k, 2=v
    int c2 = o & 15;
    int h = c2 >> 1, c = c2 & 1;
    int g = d_GRADE[a2];
    const float* w = wmv + (size_t)o * 16 * 9;
    float yy = 0.f;
    #pragma unroll
    for (int i = 0; i < 16; ++i) yy += w[i * 9 + g] * nmv[i * 16 + a2];
    int pr = d_PAIR[a2];
    if (pr >= 0) {
      int k2 = 4 + g;
      #pragma unroll
      for (int i = 0; i < 16; ++i) yy += w[i * 9 + k2] * nmv[i * 16 + pr];
    }
    if (a2 == 0) {
      const float* wr = wsm + (size_t)o * 32;
      #pragma unroll
      for (int j = 0; j < 32; ++j) yy += wr[j] * ns[j];
    }
    size_t kvb = ((size_t)(b * 8 + h)) * 1024 + n;
    if (sec == 0) {
      int ip = d_IPOS[a2];
      if (ip >= 0) q_bf[kvb * 32 + c * 8 + ip] = f2b(yy * QSCALE);
      else {
        int jp = d_JPOS[a2];
        int slot = (c == 0) ? (20 + jp) : (jp < 4 ? 28 + jp : -1);
        if (slot >= 0) q_bf[kvb * 32 + slot] = 0;
      }
    } else if (sec == 1) {
      int ip = d_IPOS[a2];
      if (ip >= 0) k_bf[kvb * 32 + c * 8 + ip] = f2b(yy);
      else {
        int jp = d_JPOS[a2];
        int slot = (c == 0) ? (20 + jp) : (jp < 4 ? 28 + jp : -1);
        if (slot >= 0) k_bf[kvb * 32 + slot] = 0;
      }
    } else {
      vT[((size_t)(b * 8 + h) * 48 + c * 16 + a2) * 1024 + n] = f2b(yy);
    }
  }
  if (t < 96) {
    float yy = 0.f;
    const float* w1 = wss + (size_t)t * 32;
    #pragma unroll
    for (int j = 0; j < 32; ++j) yy += w1[j] * ns[j];
    const float* w2 = wms + (size_t)t * 16;
    #pragma unroll
    for (int i = 0; i < 16; ++i) yy += w2[i] * nmv[i * 16];
    int sec = t >> 5, o2 = t & 31;
    int h = o2 >> 2, d = o2 & 3;
    size_t kvb = ((size_t)(b * 8 + h)) * 1024 + n;
    if (sec == 0)      q_bf[kvb * 32 + 16 + d] = f2b(yy * QSCALE);
    else if (sec == 1) k_bf[kvb * 32 + 16 + d] = f2b(yy);
    else               vT[((size_t)(b * 8 + h) * 48 + 32 + d) * 1024 + n] = f2b(yy);
  }
}

// ---------------- attention: bf16 MFMA flash ----------------
// grid = 64 (b,h) x 16 q-tiles of 64; block 256 = 4 waves; one wave owns 16 queries.
// Per 32-key tile: S^T = K x Q^T (2 MFMA), 2-shuffle softmax (keys live in lane rows),
// P^T -> A-layout via wave-private LDS round trip, O^T += V^T x P^T (3 MFMA).
__global__ void __launch_bounds__(256) k_attn(
    const ushort_t* __restrict__ q_bf, const ushort_t* __restrict__ k_bf,
    const ushort_t* __restrict__ vT, float* __restrict__ o_mv, float* __restrict__ o_s)
{
  __shared__ __align__(16) ushort_t plds[4][640];  // per wave: 16 q x 32 keys, stride 40
  int bx = blockIdx.x;
  int bh = bx >> 4, qb = bx & 15;
  int b = bh >> 3, h = bh & 7;
  int t = threadIdx.x;
  int w = t >> 6, lane = t & 63;
  int quad = lane >> 4, col = lane & 15;
  int q16 = qb * 64 + w * 16;
  size_t hb = (size_t)bh * 1024;
  ushort_t* myp = &plds[w][0];

  // Q as B-operand: lane holds Q[q=col][d=quad*8+j]  (16B contiguous)
  bf16x8 qfrag = *(const bf16x8*)(q_bf + (hb + q16 + col) * 32 + quad * 8);

  f32x4 ot0 = {0.f,0.f,0.f,0.f}, ot1 = {0.f,0.f,0.f,0.f}, ot2 = {0.f,0.f,0.f,0.f};
  float m = -1e30f, l = 0.f;

  for (int kt = 0; kt < 32; ++kt) {
    int kb = kt * 32;
    // K as A-operand: lane holds K[key=kb+tile*16+col][d=quad*8+j]
    bf16x8 kf0 = *(const bf16x8*)(k_bf + (hb + kb + col) * 32 + quad * 8);
    bf16x8 kf1 = *(const bf16x8*)(k_bf + (hb + kb + 16 + col) * 32 + quad * 8);
    // V^T as A-operand: lane holds V^T[vdim=tile*16+col][key=kb+quad*8+j]
    bf16x8 vf0 = *(const bf16x8*)(vT + ((size_t)bh * 48 +      col) * 1024 + kb + quad * 8);
    bf16x8 vf1 = *(const bf16x8*)(vT + ((size_t)bh * 48 + 16 + col) * 1024 + kb + quad * 8);
    bf16x8 vf2 = *(const bf16x8*)(vT + ((size_t)bh * 48 + 32 + col) * 1024 + kb + quad * 8);
    f32x4 zero = {0.f,0.f,0.f,0.f};
    // S^T[key=kb+(tile*16)+quad*4+r][q=col]
    f32x4 s0 = __builtin_amdgcn_mfma_f32_16x16x32_bf16(kf0, qfrag, zero, 0, 0, 0);
    f32x4 s1 = __builtin_amdgcn_mfma_f32_16x16x32_bf16(kf1, qfrag, zero, 0, 0, 0);

    float mt = fmaxf(fmaxf(fmaxf(s0[0], s0[1]), fmaxf(s0[2], s0[3])),
                     fmaxf(fmaxf(s1[0], s1[1]), fmaxf(s1[2], s1[3])));
    mt = fmaxf(mt, __shfl_xor(mt, 16, 64));
    mt = fmaxf(mt, __shfl_xor(mt, 32, 64));
    float mnew = fmaxf(m, mt);
    float corr = exp2f(m - mnew);
    float p0a = exp2f(s0[0] - mnew), p0b = exp2f(s0[1] - mnew);
    float p0c = exp2f(s0[2] - mnew), p0d = exp2f(s0[3] - mnew);
    float p1a = exp2f(s1[0] - mnew), p1b = exp2f(s1[1] - mnew);
    float p1c = exp2f(s1[2] - mnew), p1d = exp2f(s1[3] - mnew);
    float ls = ((p0a + p0b) + (p0c + p0d)) + ((p1a + p1b) + (p1c + p1d));
    ls += __shfl_xor(ls, 16, 64);
    ls += __shfl_xor(ls, 32, 64);
    l = l * corr + ls;
    m = mnew;
    ot0[0] *= corr; ot0[1] *= corr; ot0[2] *= corr; ot0[3] *= corr;
    ot1[0] *= corr; ot1[1] *= corr; ot1[2] *= corr; ot1[3] *= corr;
    ot2[0] *= corr; ot2[1] *= corr; ot2[2] *= corr; ot2[3] *= corr;

    // P[q=col][local key]: lane writes keys quad*4+0..3 and 16+quad*4+0..3
    *(ushort4*)(myp + col * 40 + quad * 4) =
        make_ushort4(f2b(p0a), f2b(p0b), f2b(p0c), f2b(p0d));
    *(ushort4*)(myp + col * 40 + 16 + quad * 4) =
        make_ushort4(f2b(p1a), f2b(p1b), f2b(p1c), f2b(p1d));
    __builtin_amdgcn_wave_barrier();
    // P^T as B-operand: lane holds P[q=col][key=quad*8+j]  (16B contiguous)
    bf16x8 pfrag = *(const bf16x8*)(myp + col * 40 + quad * 8);
    __builtin_amdgcn_wave_barrier();
    ot0 = __builtin_amdgcn_mfma_f32_16x16x32_bf16(vf0, pfrag, ot0, 0, 0, 0);
    ot1 = __builtin_amdgcn_mfma_f32_16x16x32_bf16(vf1, pfrag, ot1, 0, 0, 0);
    ot2 = __builtin_amdgcn_mfma_f32_16x16x32_bf16(vf2, pfrag, ot2, 0, 0, 0);
  }

  float invl = 1.f / l;
  int tok = b * NN + q16 + col;
  // O^T: lane holds O[q=col][vdim=tile*16+quad*4+r]
  float* op0 = o_mv + (size_t)tok * 256 + (2 * h) * 16 + quad * 4;
  op0[0] = ot0[0] * invl; op0[1] = ot0[1] * invl;
  op0[2] = ot0[2] * invl; op0[3] = ot0[3] * invl;
  float* op1 = o_mv + (size_t)tok * 256 + (2 * h + 1) * 16 + quad * 4;
  op1[0] = ot1[0] * invl; op1[1] = ot1[1] * invl;
  op1[2] = ot1[2] * invl; op1[3] = ot1[3] * invl;
  if (quad == 0) {
    float* osp = o_s + (size_t)tok * 32 + h * 4;
    osp[0] = ot2[0] * invl; osp[1] = ot2[1] * invl;
    osp[2] = ot2[2] * invl; osp[3] = ot2[3] * invl;
  }
}

// ---------------- attention out-proj + residual ----------------
__global__ void __launch_bounds__(256) k_out_res(
    const float* __restrict__ o_mv, const float* __restrict__ o_s,
    const float* __restrict__ wmv, const float* __restrict__ wsm,
    const float* __restrict__ wms, const float* __restrict__ wss,
    float* __restrict__ mv, float* __restrict__ s)
{
  __shared__ float x[256];
  __shared__ float xs[32];
  int tok = blockIdx.x, t = threadIdx.x;
  x[t] = o_mv[(size_t)tok * 256 + t];
  if (t < 32) xs[t] = o_s[(size_t)tok * 32 + t];
  __syncthreads();
  int o = t >> 4, aa = t & 15;
  int g = d_GRADE[aa];
  const float* w = wmv + (size_t)o * 16 * 9;
  float yy = 0.f;
  #pragma unroll
  for (int i = 0; i < 16; ++i) yy += w[i * 9 + g] * x[i * 16 + aa];
  int pr = d_PAIR[aa];
  if (pr >= 0) {
    int k2 = 4 + g;
    #pragma unroll
    for (int i = 0; i < 16; ++i) yy += w[i * 9 + k2] * x[i * 16 + pr];
  }
  if (aa == 0) {
    const float* wr = wsm + (size_t)o * 32;
    #pragma unroll
    for (int j = 0; j < 32; ++j) yy += wr[j] * xs[j];
  }
  mv[(size_t)tok * 256 + t] += yy;
  if (t < 32) {
    float ys = 0.f;
    const float* w1 = wss + (size_t)t * 32;
    #pragma unroll
    for (int j = 0; j < 32; ++j) ys += w1[j] * xs[j];
    const float* w2 = wms + (size_t)t * 16;
    #pragma unroll
    for (int i = 0; i < 16; ++i) ys += w2[i] * x[i * 16];
    s[(size_t)tok * 32 + t] += ys;
  }
}

// ---------------- LN + geometric MLP + residual ----------------
__global__ void __launch_bounds__(256) k_mlp_res(
    float* __restrict__ mv, float* __restrict__ s,
    const float* __restrict__ w1mv, const float* __restrict__ w1sm,
    const float* __restrict__ w1ms, const float* __restrict__ w1ss,
    const float* __restrict__ w2mv, const float* __restrict__ w2sm,
    const float* __restrict__ w2ms, const float* __restrict__ w2ss)
{
  __shared__ float nmv[256];
  __shared__ float ns[32];
  __shared__ float red[256];
  __shared__ float hmv[512];
  __shared__ float hs[64];
  __shared__ float gpl[256];
  __shared__ float shl[32];
  int tok = blockIdx.x, t = threadIdx.x;
  int aa = t & 15;
  float v = mv[(size_t)tok * 256 + t];
  float sv = (t < 32) ? s[(size_t)tok * 32 + t] : 0.f;
  red[t] = d_INNER[aa] ? v * v : 0.f;
  __syncthreads();
  for (int w = 128; w > 0; w >>= 1) { if (t < w) red[t] += red[t + w]; __syncthreads(); }
  float inv = rsqrtf(red[0] / 16.f + 1e-6f);
  __syncthreads();
  red[t] = (t < 32) ? sv * sv : 0.f;
  __syncthreads();
  for (int w = 128; w > 0; w >>= 1) { if (t < w) red[t] += red[t + w]; __syncthreads(); }
  float sinv = rsqrtf(red[0] / 32.f + 1e-6f);
  nmv[t] = v * inv;
  if (t < 32) ns[t] = sv * sinv;
  __syncthreads();

  for (int r = 0; r < 2; ++r) {
    int u = r * 256 + t;
    int o = u >> 4, a2 = u & 15;
    int g = d_GRADE[a2];
    const float* w = w1mv + (size_t)o * 16 * 9;
    float yy = 0.f;
    #pragma unroll
    for (int i = 0; i < 16; ++i) yy += w[i * 9 + g] * nmv[i * 16 + a2];
    int pr = d_PAIR[a2];
    if (pr >= 0) {
      int k2 = 4 + g;
      #pragma unroll
      for (int i = 0; i < 16; ++i) yy += w[i * 9 + k2] * nmv[i * 16 + pr];
    }
    if (a2 == 0) {
      const float* wr = w1sm + (size_t)o * 32;
      #pragma unroll
      for (int j = 0; j < 32; ++j) yy += wr[j] * ns[j];
    }
    hmv[u] = yy;
  }
  if (t < 64) {
    float yy = 0.f;
    const float* w1 = w1ss + (size_t)t * 32;
    #pragma unroll
    for (int j = 0; j < 32; ++j) yy += w1[j] * ns[j];
    const float* w2 = w1ms + (size_t)t * 16;
    #pragma unroll
    for (int i = 0; i < 16; ++i) yy += w2[i] * nmv[i * 16];
    hs[t] = yy;
  }
  __syncthreads();

  int c = t >> 4, k = t & 15;
  int mk = d_I2M[k];
  float gacc = 0.f;
  #pragma unroll
  for (int i = 0; i < 16; ++i) {
    int mi = d_I2M[i];
    int mj = mi ^ mk;
    if (mi & mj & 1) continue;  // e0 * e0 = 0
    int j = d_M2I[mj];
    int sw = 0;
    #pragma unroll
    for (int bb = 0; bb < 4; ++bb)
      if (mj & (1 << bb)) sw += __popc(((unsigned)mi) >> (bb + 1));
    float val = hmv[c * 16 + i] * hmv[256 + c * 16 + j];
    gacc += (sw & 1) ? -val : val;
  }
  gpl[t] = gacc;
  __syncthreads();
  float g0 = gpl[c * 16];
  __syncthreads();
  gpl[t] = gacc * gelu_tanh(g0);
  if (t < 32) shl[t] = hs[t] * gelu_tanh(hs[32 + t]);
  __syncthreads();

  {
    int o = t >> 4;
    int g = d_GRADE[aa];
    const float* w = w2mv + (size_t)o * 16 * 9;
    float yy = 0.f;
    #pragma unroll
    for (int i = 0; i < 16; ++i) yy += w[i * 9 + g] * gpl[i * 16 + aa];
    int pr = d_PAIR[aa];
    if (pr >= 0) {
      int k2 = 4 + g;
      #pragma unroll
      for (int i = 0; i < 16; ++i) yy += w[i * 9 + k2] * gpl[i * 16 + pr];
    }
    if (aa == 0) {
      const float* wr = w2sm + (size_t)o * 32;
      #pragma unroll
      for (int j = 0; j < 32; ++j) yy += wr[j] * shl[j];
    }
    mv[(size_t)tok * 256 + t] = v + yy;
  }
  if (t < 32) {
    float ys = 0.f;
    const float* w1 = w2ss + (size_t)t * 32;
    #pragma unroll
    for (int j = 0; j < 32; ++j) ys += w1[j] * shl[j];
    const float* w2 = w2ms + (size_t)t * 16;
    #pragma unroll
    for (int i = 0; i < 16; ++i) ys += w2[i] * gpl[i * 16];
    s[(size_t)tok * 32 + t] = sv + ys;
  }
}

// ---------------- final projection + mean ----------------
__global__ void __launch_bounds__(256) k_final(
    const float* __restrict__ mv, const float* __restrict__ s,
    const float* __restrict__ wout_mv, const float* __restrict__ wout_sm,
    float* __restrict__ out)
{
  __shared__ float red[256];
  int b = blockIdx.x, t = threadIdx.x;
  float part = 0.f;
  for (int n = t; n < NN; n += 256) {
    const float* mvp = mv + ((size_t)(b * NN + n) * 16) * 16;
    const float* sp = s + (size_t)(b * NN + n) * 32;
    float acc = 0.f;
    #pragma unroll
    for (int i = 0; i < 16; ++i) acc += wout_mv[i * 9] * mvp[i * 16];
    #pragma unroll
    for (int j = 0; j < 32; ++j) acc += wout_sm[j] * sp[j];
    part += acc;
  }
  red[t] = part;
  __syncthreads();
  for (int w = 128; w > 0; w >>= 1) { if (t < w) red[t] += red[t + w]; __syncthreads(); }
  if (t == 0) out[b] = red[0] / (float)NN;
}

extern "C" void kernel_launch(void* const* d_in, const int* in_sizes, int n_in,
                              void* d_out, int out_size, void* d_ws, size_t ws_size,
                              hipStream_t stream) {
  const float* inputs    = (const float*)d_in[0];
  const float* win_mv    = (const float*)d_in[1];
  const float* win_ms    = (const float*)d_in[2];
  const float* win_bs    = (const float*)d_in[3];
  const float* a_qkv_wmv = (const float*)d_in[4];
  const float* a_qkv_wsm = (const float*)d_in[5];
  const float* a_qkv_wms = (const float*)d_in[6];
  const float* a_qkv_wss = (const float*)d_in[7];
  const float* a_out_wmv = (const float*)d_in[8];
  const float* a_out_wsm = (const float*)d_in[9];
  const float* a_out_wms = (const float*)d_in[10];
  const float* a_out_wss = (const float*)d_in[11];
  const float* m1_wmv    = (const float*)d_in[12];
  const float* m1_wsm    = (const float*)d_in[13];
  const float* m1_wms    = (const float*)d_in[14];
  const float* m1_wss    = (const float*)d_in[15];
  const float* m2_wmv    = (const float*)d_in[16];
  const float* m2_wsm    = (const float*)d_in[17];
  const float* m2_wms    = (const float*)d_in[18];
  const float* m2_wss    = (const float*)d_in[19];
  const float* wout_mv   = (const float*)d_in[20];
  const float* wout_sm   = (const float*)d_in[21];
  float* out = (float*)d_out;

  float* ws = (float*)d_ws;
  float* mv   = ws;                  // 8*1024*256 = 2097152 f
  float* s    = mv + 2097152;        // 262144 f
  float* o_mv = s + 262144;          // 2097152 f
  float* o_s  = o_mv + 2097152;      // 262144 f
  ushort_t* q_bf = (ushort_t*)(o_s + 262144);  // 64*1024*32 = 2097152 bf16
  ushort_t* k_bf = q_bf + 2097152;             // 2097152 bf16
  ushort_t* vT   = k_bf + 2097152;             // 64*48*1024 = 3145728 bf16
  // total ~33.5 MB

  int ntok = BB * NN;
  k_embed<<<ntok, 256, 0, stream>>>(inputs, win_mv, win_ms, win_bs, mv, s);

  for (int l = 0; l < LLAYERS; ++l) {
    k_ln_qkv<<<ntok, 256, 0, stream>>>(mv, s,
        a_qkv_wmv + (size_t)l * 48 * 16 * 9, a_qkv_wsm + (size_t)l * 48 * 32,
        a_qkv_wms + (size_t)l * 96 * 16,     a_qkv_wss + (size_t)l * 96 * 32,
        q_bf, k_bf, vT);
    k_attn<<<64 * 16, 256, 0, stream>>>(q_bf, k_bf, vT, o_mv, o_s);
    k_out_res<<<ntok, 256, 0, stream>>>(o_mv, o_s,
        a_out_wmv + (size_t)l * 16 * 16 * 9, a_out_wsm + (size_t)l * 16 * 32,
        a_out_wms + (size_t)l * 32 * 16,     a_out_wss + (size_t)l * 32 * 32,
        mv, s);
    k_mlp_res<<<ntok, 256, 0, stream>>>(mv, s,
        m1_wmv + (size_t)l * 32 * 16 * 9, m1_wsm + (size_t)l * 32 * 32,
        m1_wms + (size_t)l * 64 * 16,     m1_wss + (size_t)l * 64 * 32,
        m2_wmv + (size_t)l * 16 * 16 * 9, m2_wsm + (size_t)l * 16 * 32,
        m2_wms + (size_t)l * 32 * 16,     m2_wss + (size_t)l * 32 * 32);
  }

  k_final<<<BB, 256, 0, stream>>>(mv, s, wout_mv, wout_sm, out);

  (void)in_sizes; (void)n_in; (void)out_size; (void)ws_size;
}

// Round 4
// 1297.518 us; speedup vs baseline: 4.8171x; 1.7671x over previous
//
#include <hip/hip_runtime.h>
#include <math.h>

#define BB 8
#define NN 1024
#define CC 16
#define SS 32
#define LLAYERS 8
#define HH 8

typedef unsigned short ushort_t;
typedef unsigned int uint_t;
using bf16x8 = __attribute__((ext_vector_type(8))) short;
using f32x4  = __attribute__((ext_vector_type(4))) float;

// Blade metadata (reference blade ordering):
// 0:() 1:(0) 2:(1) 3:(2) 4:(3) 5:(01) 6:(02) 7:(03) 8:(12) 9:(13) 10:(23)
// 11:(012) 12:(013) 13:(023) 14:(123) 15:(0123)
__constant__ int d_GRADE[16] = {0,1,1,1,1,2,2,2,2,2,2,3,3,3,3,4};
__constant__ int d_PAIR[16]  = {-1,0,-1,-1,-1,2,3,4,-1,-1,-1,8,9,10,-1,14};
// the 8 INNER (e0-free) blades in order
__constant__ int d_IB[8] = {0,2,3,4,8,9,10,14};
// blade index -> bitmask over {e0,e1,e2,e3}
__constant__ int d_I2M[16] = {0,1,2,4,8,3,5,9,6,10,12,7,11,13,14,15};
// bitmask -> blade index
__constant__ int d_M2I[16] = {0,1,2,5,3,6,8,11,4,7,9,12,10,13,14,15};

// softmax in log2 domain: fold 1/sqrt(20) * log2(e) into Q at pack time
#define QSCALE (0.22360679774997896f * 1.4426950408889634f)

__device__ __forceinline__ float gelu_tanh(float x) {
  float x3 = x * x * x;
  float inner = 0.7978845608028654f * (x + 0.044715f * x3);
  return 0.5f * x * (1.0f + tanhf(inner));
}

__device__ __forceinline__ ushort_t f2b(float f) {
  union { float f; unsigned int u; } x;
  x.f = f;
  unsigned int r = x.u + 0x7fffu + ((x.u >> 16) & 1u);  // RNE
  return (ushort_t)(r >> 16);
}

// ---------------- embed ----------------
__global__ void __launch_bounds__(256) k_embed(
    const float* __restrict__ inp, const float* __restrict__ win_mv,
    const float* __restrict__ win_ms, const float* __restrict__ win_bs,
    float* __restrict__ mv, float* __restrict__ s)
{
  int tok = blockIdx.x, t = threadIdx.x;
  float x = inp[tok * 3 + 0];
  float y = inp[tok * 3 + 1];
  float z = inp[tok * 3 + 2];
  int o = t >> 4, aa = t & 15;
  float ma = (aa == 14) ? 1.f : (aa == 13) ? -x : (aa == 12) ? y : (aa == 11) ? -z : 0.f;
  int g = d_GRADE[aa];
  float val = win_mv[o * 9 + g] * ma;
  int pr = d_PAIR[aa];
  if (pr >= 0) {
    float mp = (pr == 14) ? 1.f : 0.f;
    val += win_mv[o * 9 + 4 + g] * mp;
  }
  mv[(size_t)tok * 256 + t] = val;
  if (t < 32) s[(size_t)tok * 32 + t] = win_bs[t];
  (void)win_ms;
}

// ---------------- LN + QKV projection, 8-token tile ----------------
__global__ void __launch_bounds__(256) k_ln_qkv(
    const float* __restrict__ mv, const float* __restrict__ s,
    const float* __restrict__ wmv, const float* __restrict__ wsm,
    const float* __restrict__ wms, const float* __restrict__ wss,
    ushort_t* __restrict__ q_bf, ushort_t* __restrict__ k_bf, ushort_t* __restrict__ vT)
{
  __shared__ float pool[9600];
  float* xmv = pool;           // [8][256]
  float* xs  = pool + 2048;    // [8][32]
  float* yst = pool + 2304;    // [8][48] rows, stride 17
  float* sst = pool + 8832;    // [8][96]

  int t = threadIdx.x;
  int tok0 = blockIdx.x * 8;
  int b = tok0 >> 10, n0 = tok0 & 1023;
  int a = t & 15, og = t >> 4;
  int g = d_GRADE[a], pr = d_PAIR[a];

  // weights -> registers (loop-invariant over the 8 tokens)
  float wgq[16], wpq[16], wgk[16], wpk[16], wgv[16], wpv[16];
  #pragma unroll
  for (int i = 0; i < 16; ++i) {
    wgq[i] = wmv[(og)      * 144 + i * 9 + g];
    wgk[i] = wmv[(16 + og) * 144 + i * 9 + g];
    wgv[i] = wmv[(32 + og) * 144 + i * 9 + g];
    wpq[i] = wmv[(og)      * 144 + i * 9 + 4 + g];
    wpk[i] = wmv[(16 + og) * 144 + i * 9 + 4 + g];
    wpv[i] = wmv[(32 + og) * 144 + i * 9 + 4 + g];
  }

  // stage inputs (coalesced)
  #pragma unroll
  for (int j = 0; j < 2; ++j)
    *(float4*)&xmv[t * 4 + j * 1024] = *(const float4*)&mv[(size_t)tok0 * 256 + t * 4 + j * 1024];
  if (t < 64)
    *(float4*)&xs[t * 4] = *(const float4*)&s[(size_t)tok0 * 32 + t * 4];
  __syncthreads();

  // LN: 16 lanes per token
  if (t < 128) {
    int tk = t >> 4, ch = t & 15;
    float* xp = &xmv[tk * 256 + ch * 16];
    float4 v0 = *(float4*)&xp[0], v1 = *(float4*)&xp[4];
    float4 v2 = *(float4*)&xp[8], v3 = *(float4*)&xp[12];
    float ss = v0.x*v0.x + v0.z*v0.z + v0.w*v0.w + v1.x*v1.x
             + v2.x*v2.x + v2.y*v2.y + v2.z*v2.z + v3.z*v3.z;
    ss += __shfl_xor(ss, 1); ss += __shfl_xor(ss, 2);
    ss += __shfl_xor(ss, 4); ss += __shfl_xor(ss, 8);
    float inv = rsqrtf(ss / 16.f + 1e-6f);
    v0.x*=inv; v0.y*=inv; v0.z*=inv; v0.w*=inv;
    v1.x*=inv; v1.y*=inv; v1.z*=inv; v1.w*=inv;
    v2.x*=inv; v2.y*=inv; v2.z*=inv; v2.w*=inv;
    v3.x*=inv; v3.y*=inv; v3.z*=inv; v3.w*=inv;
    *(float4*)&xp[0] = v0; *(float4*)&xp[4] = v1;
    *(float4*)&xp[8] = v2; *(float4*)&xp[12] = v3;
    float s0 = xs[tk * 32 + ch * 2], s1 = xs[tk * 32 + ch * 2 + 1];
    float s2 = s0 * s0 + s1 * s1;
    s2 += __shfl_xor(s2, 1); s2 += __shfl_xor(s2, 2);
    s2 += __shfl_xor(s2, 4); s2 += __shfl_xor(s2, 8);
    float sinv = rsqrtf(s2 / 32.f + 1e-6f);
    xs[tk * 32 + ch * 2] = s0 * sinv;
    xs[tk * 32 + ch * 2 + 1] = s1 * sinv;
  }
  __syncthreads();

  // main projection: thread owns (q-ch og, k-ch og, v-ch og) x blade a
  for (int tk = 0; tk < 8; ++tk) {
    float y0 = 0.f, y1 = 0.f, y2 = 0.f;
    const float* xb = &xmv[tk * 256];
    #pragma unroll
    for (int i = 0; i < 16; ++i) {
      float xa_ = xb[i * 16 + a];
      y0 += wgq[i] * xa_; y1 += wgk[i] * xa_; y2 += wgv[i] * xa_;
    }
    if (pr >= 0) {
      #pragma unroll
      for (int i = 0; i < 16; ++i) {
        float xp_ = xb[i * 16 + pr];
        y0 += wpq[i] * xp_; y1 += wpk[i] * xp_; y2 += wpv[i] * xp_;
      }
    }
    yst[(tk * 48 + og) * 17 + a] = y0;
    yst[(tk * 48 + 16 + og) * 17 + a] = y1;
    yst[(tk * 48 + 32 + og) * 17 + a] = y2;
  }
  __syncthreads();

  // wsm term into blade-0 column + scalar outputs
  for (int u = t; u < 384; u += 256) {
    int tk = u / 48, o = u % 48;
    float add = 0.f;
    #pragma unroll
    for (int j = 0; j < 32; ++j) add += wsm[o * 32 + j] * xs[tk * 32 + j];
    yst[(tk * 48 + o) * 17 + 0] += add;
  }
  for (int u = t; u < 768; u += 256) {
    int tk = u / 96, o96 = u % 96;
    float yy = 0.f;
    #pragma unroll
    for (int j = 0; j < 32; ++j) yy += wss[o96 * 32 + j] * xs[tk * 32 + j];
    #pragma unroll
    for (int i = 0; i < 16; ++i) yy += wms[o96 * 16 + i] * xmv[tk * 256 + i * 16];
    sst[tk * 96 + o96] = yy;
  }
  __syncthreads();

  // pack q/k rows (64B vector stores)
  if (t < 128) {
    int isK = t >> 6;
    int r = t & 63;
    int tk = r >> 3, h = r & 7;
    float scale = isK ? 1.f : QSCALE;
    const float* base = &yst[(tk * 48 + isK * 16) * 17];
    ushort_t tmp[32];
    #pragma unroll
    for (int j = 0; j < 8; ++j) {
      int blade = d_IB[j];
      tmp[j]     = f2b(base[(2 * h)     * 17 + blade] * scale);
      tmp[8 + j] = f2b(base[(2 * h + 1) * 17 + blade] * scale);
    }
    #pragma unroll
    for (int d = 0; d < 4; ++d)
      tmp[16 + d] = f2b(sst[tk * 96 + isK * 32 + h * 4 + d] * scale);
    #pragma unroll
    for (int j2 = 20; j2 < 32; ++j2) tmp[j2] = 0;
    uint_t out[16];
    #pragma unroll
    for (int j3 = 0; j3 < 16; ++j3)
      out[j3] = (uint_t)tmp[2 * j3] | ((uint_t)tmp[2 * j3 + 1] << 16);
    ushort_t* dst = (isK ? k_bf : q_bf) + ((size_t)(b * 8 + h) * 1024 + n0 + tk) * 32;
    *(uint4*)(dst +  0) = make_uint4(out[0],  out[1],  out[2],  out[3]);
    *(uint4*)(dst +  8) = make_uint4(out[4],  out[5],  out[6],  out[7]);
    *(uint4*)(dst + 16) = make_uint4(out[8],  out[9],  out[10], out[11]);
    *(uint4*)(dst + 24) = make_uint4(out[12], out[13], out[14], out[15]);
  }
  // pack vT mv-dim rows (16B per row of 8 tokens)
  {
    int h = t >> 5, dim = t & 31;
    int ch = 2 * h + (dim >> 4), blade = dim & 15;
    uint_t ov[4];
    #pragma unroll
    for (int tk = 0; tk < 8; ++tk) {
      ushort_t bv = f2b(yst[(tk * 48 + 32 + ch) * 17 + blade]);
      if (tk & 1) ov[tk >> 1] |= ((uint_t)bv) << 16; else ov[tk >> 1] = bv;
    }
    ushort_t* dst = vT + ((size_t)(b * 8 + h) * 48 + dim) * 1024 + n0;
    *(uint4*)dst = make_uint4(ov[0], ov[1], ov[2], ov[3]);
  }
  // pack vT scalar-dim rows
  if (t < 32) {
    int h = t >> 2, d = t & 3;
    uint_t ov[4];
    #pragma unroll
    for (int tk = 0; tk < 8; ++tk) {
      ushort_t bv = f2b(sst[tk * 96 + 64 + h * 4 + d]);
      if (tk & 1) ov[tk >> 1] |= ((uint_t)bv) << 16; else ov[tk >> 1] = bv;
    }
    ushort_t* dst = vT + ((size_t)(b * 8 + h) * 48 + 32 + d) * 1024 + n0;
    *(uint4*)dst = make_uint4(ov[0], ov[1], ov[2], ov[3]);
  }
}

// ---------------- attention: bf16 MFMA flash (unchanged from R3) ----------------
__global__ void __launch_bounds__(256) k_attn(
    const ushort_t* __restrict__ q_bf, const ushort_t* __restrict__ k_bf,
    const ushort_t* __restrict__ vT, float* __restrict__ o_mv, float* __restrict__ o_s)
{
  __shared__ __align__(16) ushort_t plds[4][640];
  int bx = blockIdx.x;
  int bh = bx >> 4, qb = bx & 15;
  int b = bh >> 3, h = bh & 7;
  int t = threadIdx.x;
  int w = t >> 6, lane = t & 63;
  int quad = lane >> 4, col = lane & 15;
  int q16 = qb * 64 + w * 16;
  size_t hb = (size_t)bh * 1024;
  ushort_t* myp = &plds[w][0];

  bf16x8 qfrag = *(const bf16x8*)(q_bf + (hb + q16 + col) * 32 + quad * 8);

  f32x4 ot0 = {0.f,0.f,0.f,0.f}, ot1 = {0.f,0.f,0.f,0.f}, ot2 = {0.f,0.f,0.f,0.f};
  float m = -1e30f, l = 0.f;

  for (int kt = 0; kt < 32; ++kt) {
    int kb = kt * 32;
    bf16x8 kf0 = *(const bf16x8*)(k_bf + (hb + kb + col) * 32 + quad * 8);
    bf16x8 kf1 = *(const bf16x8*)(k_bf + (hb + kb + 16 + col) * 32 + quad * 8);
    bf16x8 vf0 = *(const bf16x8*)(vT + ((size_t)bh * 48 +      col) * 1024 + kb + quad * 8);
    bf16x8 vf1 = *(const bf16x8*)(vT + ((size_t)bh * 48 + 16 + col) * 1024 + kb + quad * 8);
    bf16x8 vf2 = *(const bf16x8*)(vT + ((size_t)bh * 48 + 32 + col) * 1024 + kb + quad * 8);
    f32x4 zero = {0.f,0.f,0.f,0.f};
    f32x4 s0 = __builtin_amdgcn_mfma_f32_16x16x32_bf16(kf0, qfrag, zero, 0, 0, 0);
    f32x4 s1 = __builtin_amdgcn_mfma_f32_16x16x32_bf16(kf1, qfrag, zero, 0, 0, 0);

    float mt = fmaxf(fmaxf(fmaxf(s0[0], s0[1]), fmaxf(s0[2], s0[3])),
                     fmaxf(fmaxf(s1[0], s1[1]), fmaxf(s1[2], s1[3])));
    mt = fmaxf(mt, __shfl_xor(mt, 16, 64));
    mt = fmaxf(mt, __shfl_xor(mt, 32, 64));
    float mnew = fmaxf(m, mt);
    float corr = exp2f(m - mnew);
    float p0a = exp2f(s0[0] - mnew), p0b = exp2f(s0[1] - mnew);
    float p0c = exp2f(s0[2] - mnew), p0d = exp2f(s0[3] - mnew);
    float p1a = exp2f(s1[0] - mnew), p1b = exp2f(s1[1] - mnew);
    float p1c = exp2f(s1[2] - mnew), p1d = exp2f(s1[3] - mnew);
    float ls = ((p0a + p0b) + (p0c + p0d)) + ((p1a + p1b) + (p1c + p1d));
    ls += __shfl_xor(ls, 16, 64);
    ls += __shfl_xor(ls, 32, 64);
    l = l * corr + ls;
    m = mnew;
    ot0[0] *= corr; ot0[1] *= corr; ot0[2] *= corr; ot0[3] *= corr;
    ot1[0] *= corr; ot1[1] *= corr; ot1[2] *= corr; ot1[3] *= corr;
    ot2[0] *= corr; ot2[1] *= corr; ot2[2] *= corr; ot2[3] *= corr;

    *(ushort4*)(myp + col * 40 + quad * 4) =
        make_ushort4(f2b(p0a), f2b(p0b), f2b(p0c), f2b(p0d));
    *(ushort4*)(myp + col * 40 + 16 + quad * 4) =
        make_ushort4(f2b(p1a), f2b(p1b), f2b(p1c), f2b(p1d));
    __builtin_amdgcn_wave_barrier();
    bf16x8 pfrag = *(const bf16x8*)(myp + col * 40 + quad * 8);
    __builtin_amdgcn_wave_barrier();
    ot0 = __builtin_amdgcn_mfma_f32_16x16x32_bf16(vf0, pfrag, ot0, 0, 0, 0);
    ot1 = __builtin_amdgcn_mfma_f32_16x16x32_bf16(vf1, pfrag, ot1, 0, 0, 0);
    ot2 = __builtin_amdgcn_mfma_f32_16x16x32_bf16(vf2, pfrag, ot2, 0, 0, 0);
  }

  float invl = 1.f / l;
  int tok = b * NN + q16 + col;
  float* op0 = o_mv + (size_t)tok * 256 + (2 * h) * 16 + quad * 4;
  op0[0] = ot0[0] * invl; op0[1] = ot0[1] * invl;
  op0[2] = ot0[2] * invl; op0[3] = ot0[3] * invl;
  float* op1 = o_mv + (size_t)tok * 256 + (2 * h + 1) * 16 + quad * 4;
  op1[0] = ot1[0] * invl; op1[1] = ot1[1] * invl;
  op1[2] = ot1[2] * invl; op1[3] = ot1[3] * invl;
  if (quad == 0) {
    float* osp = o_s + (size_t)tok * 32 + h * 4;
    osp[0] = ot2[0] * invl; osp[1] = ot2[1] * invl;
    osp[2] = ot2[2] * invl; osp[3] = ot2[3] * invl;
  }
}

// ---------------- attention out-proj + residual, 8-token tile ----------------
__global__ void __launch_bounds__(256) k_out_res(
    const float* __restrict__ o_mv, const float* __restrict__ o_s,
    const float* __restrict__ wmv, const float* __restrict__ wsm,
    const float* __restrict__ wms, const float* __restrict__ wss,
    float* __restrict__ mv, float* __restrict__ s)
{
  __shared__ float pool[4480];
  float* xo  = pool;          // [8][256]
  float* xso = pool + 2048;   // [8][32]
  float* yst = pool + 2304;   // [8][16] rows, stride 17

  int t = threadIdx.x;
  int tok0 = blockIdx.x * 8;
  int a = t & 15, og = t >> 4;
  int g = d_GRADE[a], pr = d_PAIR[a];

  float wg[16], wp[16];
  #pragma unroll
  for (int i = 0; i < 16; ++i) {
    wg[i] = wmv[og * 144 + i * 9 + g];
    wp[i] = wmv[og * 144 + i * 9 + 4 + g];
  }

  #pragma unroll
  for (int j = 0; j < 2; ++j)
    *(float4*)&xo[t * 4 + j * 1024] = *(const float4*)&o_mv[(size_t)tok0 * 256 + t * 4 + j * 1024];
  if (t < 64)
    *(float4*)&xso[t * 4] = *(const float4*)&o_s[(size_t)tok0 * 32 + t * 4];
  __syncthreads();

  for (int tk = 0; tk < 8; ++tk) {
    float y = 0.f;
    const float* xb = &xo[tk * 256];
    #pragma unroll
    for (int i = 0; i < 16; ++i) y += wg[i] * xb[i * 16 + a];
    if (pr >= 0) {
      #pragma unroll
      for (int i = 0; i < 16; ++i) y += wp[i] * xb[i * 16 + pr];
    }
    yst[(tk * 16 + og) * 17 + a] = y;
  }
  __syncthreads();

  if (t < 128) {
    int tk = t >> 4, o = t & 15;
    float add = 0.f;
    #pragma unroll
    for (int j = 0; j < 32; ++j) add += wsm[o * 32 + j] * xso[tk * 32 + j];
    yst[(tk * 16 + o) * 17 + 0] += add;
  }
  {
    int o32 = t & 31, tk = t >> 5;
    float ys = 0.f;
    #pragma unroll
    for (int j = 0; j < 32; ++j) ys += wss[o32 * 32 + j] * xso[tk * 32 + j];
    #pragma unroll
    for (int i = 0; i < 16; ++i) ys += wms[o32 * 16 + i] * xo[tk * 256 + i * 16];
    s[(size_t)(tok0 + tk) * 32 + o32] += ys;
  }
  __syncthreads();

  #pragma unroll
  for (int p = 0; p < 8; ++p) {
    int flat = p * 256 + t;
    int tk = flat >> 8, rem = flat & 255, o = rem >> 4, a2 = rem & 15;
    mv[(size_t)tok0 * 256 + flat] += yst[(tk * 16 + o) * 17 + a2];
  }
}

// ---------------- LN + geometric MLP + residual, 8-token tile ----------------
__global__ void __launch_bounds__(256) k_mlp_res(
    float* __restrict__ mv, float* __restrict__ s,
    const float* __restrict__ w1mv, const float* __restrict__ w1sm,
    const float* __restrict__ w1ms, const float* __restrict__ w1ss,
    const float* __restrict__ w2mv, const float* __restrict__ w2sm,
    const float* __restrict__ w2ms, const float* __restrict__ w2ss)
{
  __shared__ float pool[9600];
  float* xmv  = pool;           // [8][256]
  float* xs   = pool + 2048;    // [8][32]
  float* hst  = pool + 2304;    // [8][32] rows, stride 17  (aliased by y2st later)
  float* y2st = pool + 2304;    // [8][16] rows, stride 17  (alias of hst)
  float* hsst = pool + 6656;    // [8][64]
  float* gst  = pool + 7168;    // [8][16] rows, stride 17
  float* shst = pool + 9344;    // [8][32]

  int t = threadIdx.x;
  int tok0 = blockIdx.x * 8;
  int a = t & 15, og = t >> 4;
  int g = d_GRADE[a], pr = d_PAIR[a];

  // GP sign/index packing for output blade k=a
  unsigned long long jpack = 0; unsigned int spack = 0, skipm = 0;
  {
    int mk = d_I2M[a];
    for (int i = 0; i < 16; ++i) {
      int mi = d_I2M[i];
      int mj = mi ^ mk;
      if (mi & mj & 1) { skipm |= 1u << i; continue; }
      int j = d_M2I[mj];
      int sw = 0;
      for (int bb2 = 0; bb2 < 4; ++bb2)
        if (mj & (1 << bb2)) sw += __popc(((unsigned)mi) >> (bb2 + 1));
      jpack |= (unsigned long long)j << (4 * i);
      spack |= (unsigned)(sw & 1) << i;
    }
  }

  float wg1a[16], wp1a[16], wg1b[16], wp1b[16];
  #pragma unroll
  for (int i = 0; i < 16; ++i) {
    wg1a[i] = w1mv[(og)      * 144 + i * 9 + g];
    wg1b[i] = w1mv[(16 + og) * 144 + i * 9 + g];
    wp1a[i] = w1mv[(og)      * 144 + i * 9 + 4 + g];
    wp1b[i] = w1mv[(16 + og) * 144 + i * 9 + 4 + g];
  }

  #pragma unroll
  for (int j = 0; j < 2; ++j)
    *(float4*)&xmv[t * 4 + j * 1024] = *(const float4*)&mv[(size_t)tok0 * 256 + t * 4 + j * 1024];
  if (t < 64)
    *(float4*)&xs[t * 4] = *(const float4*)&s[(size_t)tok0 * 32 + t * 4];
  __syncthreads();

  if (t < 128) {
    int tk = t >> 4, ch = t & 15;
    float* xp = &xmv[tk * 256 + ch * 16];
    float4 v0 = *(float4*)&xp[0], v1 = *(float4*)&xp[4];
    float4 v2 = *(float4*)&xp[8], v3 = *(float4*)&xp[12];
    float ss = v0.x*v0.x + v0.z*v0.z + v0.w*v0.w + v1.x*v1.x
             + v2.x*v2.x + v2.y*v2.y + v2.z*v2.z + v3.z*v3.z;
    ss += __shfl_xor(ss, 1); ss += __shfl_xor(ss, 2);
    ss += __shfl_xor(ss, 4); ss += __shfl_xor(ss, 8);
    float inv = rsqrtf(ss / 16.f + 1e-6f);
    v0.x*=inv; v0.y*=inv; v0.z*=inv; v0.w*=inv;
    v1.x*=inv; v1.y*=inv; v1.z*=inv; v1.w*=inv;
    v2.x*=inv; v2.y*=inv; v2.z*=inv; v2.w*=inv;
    v3.x*=inv; v3.y*=inv; v3.z*=inv; v3.w*=inv;
    *(float4*)&xp[0] = v0; *(float4*)&xp[4] = v1;
    *(float4*)&xp[8] = v2; *(float4*)&xp[12] = v3;
    float s0 = xs[tk * 32 + ch * 2], s1 = xs[tk * 32 + ch * 2 + 1];
    float s2 = s0 * s0 + s1 * s1;
    s2 += __shfl_xor(s2, 1); s2 += __shfl_xor(s2, 2);
    s2 += __shfl_xor(s2, 4); s2 += __shfl_xor(s2, 8);
    float sinv = rsqrtf(s2 / 32.f + 1e-6f);
    xs[tk * 32 + ch * 2] = s0 * sinv;
    xs[tk * 32 + ch * 2 + 1] = s1 * sinv;
  }
  __syncthreads();

  // h1 = equi_linear1 (32 mv channels)
  for (int tk = 0; tk < 8; ++tk) {
    float y0 = 0.f, y1 = 0.f;
    const float* xb = &xmv[tk * 256];
    #pragma unroll
    for (int i = 0; i < 16; ++i) {
      float xa_ = xb[i * 16 + a];
      y0 += wg1a[i] * xa_; y1 += wg1b[i] * xa_;
    }
    if (pr >= 0) {
      #pragma unroll
      for (int i = 0; i < 16; ++i) {
        float xp_ = xb[i * 16 + pr];
        y0 += wp1a[i] * xp_; y1 += wp1b[i] * xp_;
      }
    }
    hst[(tk * 32 + og) * 17 + a] = y0;
    hst[(tk * 32 + 16 + og) * 17 + a] = y1;
  }
  // scalar h (64 per token)
  for (int u = t; u < 512; u += 256) {
    int tk = u >> 6, o64 = u & 63;
    float yy = 0.f;
    #pragma unroll
    for (int j = 0; j < 32; ++j) yy += w1ss[o64 * 32 + j] * xs[tk * 32 + j];
    #pragma unroll
    for (int i = 0; i < 16; ++i) yy += w1ms[o64 * 16 + i] * xmv[tk * 256 + i * 16];
    hsst[tk * 64 + o64] = yy;
  }
  __syncthreads();

  // w1sm into blade-0 column
  {
    int tk = t >> 5, o = t & 31;
    float add = 0.f;
    #pragma unroll
    for (int j = 0; j < 32; ++j) add += w1sm[o * 32 + j] * xs[tk * 32 + j];
    hst[(tk * 32 + o) * 17 + 0] += add;
  }
  __syncthreads();

  // geometric product + gate
  for (int tk = 0; tk < 8; ++tk) {
    const float* h1b = &hst[(tk * 32 + og) * 17];
    const float* h2b = &hst[(tk * 32 + 16 + og) * 17];
    float gacc = 0.f;
    #pragma unroll
    for (int i = 0; i < 16; ++i) {
      int j = (int)((jpack >> (4 * i)) & 15ull);
      float val = h1b[i] * h2b[j];
      float sv = ((spack >> i) & 1) ? -val : val;
      gacc += ((skipm >> i) & 1) ? 0.f : sv;
    }
    float gp0 = __shfl(gacc, (int)(t & 48), 64);
    gst[(tk * 16 + og) * 17 + a] = gacc * gelu_tanh(gp0);
  }
  // scalar gate
  {
    int tk = t >> 5, o32 = t & 31;
    shst[tk * 32 + o32] = hsst[tk * 64 + o32] * gelu_tanh(hsst[tk * 64 + 32 + o32]);
  }
  __syncthreads();

  // equi_linear2 (writes y2st, aliased onto hst region — hst is dead now)
  {
    float wg2[16], wp2[16];
    #pragma unroll
    for (int i = 0; i < 16; ++i) {
      wg2[i] = w2mv[og * 144 + i * 9 + g];
      wp2[i] = w2mv[og * 144 + i * 9 + 4 + g];
    }
    for (int tk = 0; tk < 8; ++tk) {
      float y = 0.f;
      #pragma unroll
      for (int i = 0; i < 16; ++i) y += wg2[i] * gst[(tk * 16 + i) * 17 + a];
      if (pr >= 0) {
        #pragma unroll
        for (int i = 0; i < 16; ++i) y += wp2[i] * gst[(tk * 16 + i) * 17 + pr];
      }
      y2st[(tk * 16 + og) * 17 + a] = y;
    }
  }
  __syncthreads();

  // w2sm into blade-0 column + s residual
  if (t < 128) {
    int tk = t >> 4, o = t & 15;
    float add = 0.f;
    #pragma unroll
    for (int j = 0; j < 32; ++j) add += w2sm[o * 32 + j] * shst[tk * 32 + j];
    y2st[(tk * 16 + o) * 17 + 0] += add;
  }
  {
    int tk = t >> 5, o32 = t & 31;
    float ys = 0.f;
    #pragma unroll
    for (int j = 0; j < 32; ++j) ys += w2ss[o32 * 32 + j] * shst[tk * 32 + j];
    #pragma unroll
    for (int i = 0; i < 16; ++i) ys += w2ms[o32 * 16 + i] * gst[(tk * 16 + i) * 17 + 0];
    s[(size_t)(tok0 + tk) * 32 + o32] += ys;
  }
  __syncthreads();

  // mv residual
  #pragma unroll
  for (int p = 0; p < 8; ++p) {
    int flat = p * 256 + t;
    int tk = flat >> 8, rem = flat & 255, o = rem >> 4, a2 = rem & 15;
    mv[(size_t)tok0 * 256 + flat] += y2st[(tk * 16 + o) * 17 + a2];
  }
}

// ---------------- final projection + mean ----------------
__global__ void __launch_bounds__(256) k_final(
    const float* __restrict__ mv, const float* __restrict__ s,
    const float* __restrict__ wout_mv, const float* __restrict__ wout_sm,
    float* __restrict__ out)
{
  __shared__ float red[256];
  int b = blockIdx.x, t = threadIdx.x;
  float part = 0.f;
  for (int n = t; n < NN; n += 256) {
    const float* mvp = mv + ((size_t)(b * NN + n) * 16) * 16;
    const float* sp = s + (size_t)(b * NN + n) * 32;
    float acc = 0.f;
    #pragma unroll
    for (int i = 0; i < 16; ++i) acc += wout_mv[i * 9] * mvp[i * 16];
    #pragma unroll
    for (int j = 0; j < 32; ++j) acc += wout_sm[j] * sp[j];
    part += acc;
  }
  red[t] = part;
  __syncthreads();
  for (int w = 128; w > 0; w >>= 1) { if (t < w) red[t] += red[t + w]; __syncthreads(); }
  if (t == 0) out[b] = red[0] / (float)NN;
}

extern "C" void kernel_launch(void* const* d_in, const int* in_sizes, int n_in,
                              void* d_out, int out_size, void* d_ws, size_t ws_size,
                              hipStream_t stream) {
  const float* inputs    = (const float*)d_in[0];
  const float* win_mv    = (const float*)d_in[1];
  const float* win_ms    = (const float*)d_in[2];
  const float* win_bs    = (const float*)d_in[3];
  const float* a_qkv_wmv = (const float*)d_in[4];
  const float* a_qkv_wsm = (const float*)d_in[5];
  const float* a_qkv_wms = (const float*)d_in[6];
  const float* a_qkv_wss = (const float*)d_in[7];
  const float* a_out_wmv = (const float*)d_in[8];
  const float* a_out_wsm = (const float*)d_in[9];
  const float* a_out_wms = (const float*)d_in[10];
  const float* a_out_wss = (const float*)d_in[11];
  const float* m1_wmv    = (const float*)d_in[12];
  const float* m1_wsm    = (const float*)d_in[13];
  const float* m1_wms    = (const float*)d_in[14];
  const float* m1_wss    = (const float*)d_in[15];
  const float* m2_wmv    = (const float*)d_in[16];
  const float* m2_wsm    = (const float*)d_in[17];
  const float* m2_wms    = (const float*)d_in[18];
  const float* m2_wss    = (const float*)d_in[19];
  const float* wout_mv   = (const float*)d_in[20];
  const float* wout_sm   = (const float*)d_in[21];
  float* out = (float*)d_out;

  float* ws = (float*)d_ws;
  float* mv   = ws;                  // 8*1024*256 = 2097152 f
  float* s    = mv + 2097152;        // 262144 f
  float* o_mv = s + 262144;          // 2097152 f
  float* o_s  = o_mv + 2097152;      // 262144 f
  ushort_t* q_bf = (ushort_t*)(o_s + 262144);  // 64*1024*32 = 2097152 bf16
  ushort_t* k_bf = q_bf + 2097152;             // 2097152 bf16
  ushort_t* vT   = k_bf + 2097152;             // 64*48*1024 = 3145728 bf16

  int ntok = BB * NN;
  int ntile = ntok / 8;  // 1024
  k_embed<<<ntok, 256, 0, stream>>>(inputs, win_mv, win_ms, win_bs, mv, s);

  for (int l = 0; l < LLAYERS; ++l) {
    k_ln_qkv<<<ntile, 256, 0, stream>>>(mv, s,
        a_qkv_wmv + (size_t)l * 48 * 16 * 9, a_qkv_wsm + (size_t)l * 48 * 32,
        a_qkv_wms + (size_t)l * 96 * 16,     a_qkv_wss + (size_t)l * 96 * 32,
        q_bf, k_bf, vT);
    k_attn<<<64 * 16, 256, 0, stream>>>(q_bf, k_bf, vT, o_mv, o_s);
    k_out_res<<<ntile, 256, 0, stream>>>(o_mv, o_s,
        a_out_wmv + (size_t)l * 16 * 16 * 9, a_out_wsm + (size_t)l * 16 * 32,
        a_out_wms + (size_t)l * 32 * 16,     a_out_wss + (size_t)l * 32 * 32,
        mv, s);
    k_mlp_res<<<ntile, 256, 0, stream>>>(mv, s,
        m1_wmv + (size_t)l * 32 * 16 * 9, m1_wsm + (size_t)l * 32 * 32,
        m1_wms + (size_t)l * 64 * 16,     m1_wss + (size_t)l * 64 * 32,
        m2_wmv + (size_t)l * 16 * 16 * 9, m2_wsm + (size_t)l * 16 * 32,
        m2_wms + (size_t)l * 32 * 16,     m2_wss + (size_t)l * 32 * 32);
  }

  k_final<<<BB, 256, 0, stream>>>(mv, s, wout_mv, wout_sm, out);

  (void)in_sizes; (void)n_in; (void)out_size; (void)ws_size;
}